// Round 2
// baseline (1656.739 us; speedup 1.0000x reference)
//
#include <hip/hip_runtime.h>

#define N_DST 100000
#define DIN 128
#define HDIM 64
#define RREL 3
#define NE 1000000

// ---------------- GEMM: h = A @ W + b  (4 matrices: dst + 3 relations) ----------------
// 64-row x 64-col tile per block, 256 threads, 4x4 register tile per thread.
__global__ __launch_bounds__(256) void k_gemm(
    const float* __restrict__ dst_feat, const float* __restrict__ neigh,
    const float* __restrict__ Wt, const float* __restrict__ bt,
    float* __restrict__ h_dst, float* __restrict__ h_src) {
  const int RB = (N_DST + 63) / 64;  // 1563 row-blocks per matrix
  int mat = blockIdx.x / RB;
  int row0 = (blockIdx.x % RB) * 64;
  const float* A = (mat == 0) ? dst_feat : (neigh + (size_t)(mat - 1) * N_DST * DIN);
  float* Hout = (mat == 0) ? h_dst : (h_src + (size_t)(mat - 1) * N_DST * HDIM);
  const float* W = Wt + (size_t)mat * DIN * HDIM;
  const float* b = bt + mat * HDIM;

  __shared__ float Wl[DIN * HDIM];  // 32 KB
  __shared__ float Al[64 * 36];     // 64 rows x 32-k chunk, stride 36 (bank-safe), 9.2 KB

  int tid = threadIdx.x;
  for (int i = tid * 4; i < DIN * HDIM; i += 1024)
    *(float4*)(Wl + i) = *(const float4*)(W + i);

  int tc = tid & 15;  // cols 4*tc .. 4*tc+3
  int tr = tid >> 4;  // rows 4*tr .. 4*tr+3
  float acc[4][4] = {};

  for (int k0 = 0; k0 < DIN; k0 += 32) {
    __syncthreads();
    for (int s = tid; s < 512; s += 256) {
      int r = s >> 3;
      int kq = (s & 7) << 2;
      int gr = row0 + r;
      if (gr >= N_DST) gr = N_DST - 1;  // clamp (tail block)
      *(float4*)(Al + r * 36 + kq) = *(const float4*)(A + (size_t)gr * DIN + k0 + kq);
    }
    __syncthreads();
#pragma unroll
    for (int kk = 0; kk < 32; kk += 4) {
      float4 av[4], wv[4];
#pragma unroll
      for (int i = 0; i < 4; i++) av[i] = *(float4*)(Al + (4 * tr + i) * 36 + kk);
#pragma unroll
      for (int j = 0; j < 4; j++) wv[j] = *(float4*)(Wl + (k0 + kk + j) * HDIM + 4 * tc);
#pragma unroll
      for (int i = 0; i < 4; i++) {
        const float* ap = (const float*)&av[i];
#pragma unroll
        for (int j = 0; j < 4; j++) {
          const float* wp = (const float*)&wv[j];
          float a = ap[j];
#pragma unroll
          for (int c = 0; c < 4; c++) acc[i][c] += a * wp[c];
        }
      }
    }
  }
#pragma unroll
  for (int i = 0; i < 4; i++) {
    int gr = row0 + 4 * tr + i;
    if (gr < N_DST) {
      float4 o;
      float* op = (float*)&o;
#pragma unroll
      for (int c = 0; c < 4; c++) op[c] = acc[i][c] + b[4 * tc + c];
      *(float4*)(Hout + (size_t)gr * HDIM + 4 * tc) = o;
    }
  }
}

// ---------------- per-node attention logits: er[r][n]=h_dst[n].ar[r], el[r][n]=h_src[r][n].al[r]
__global__ __launch_bounds__(256) void k_logits(
    const float* __restrict__ h_dst, const float* __restrict__ h_src,
    const float* __restrict__ attn_l, const float* __restrict__ attn_r,
    float* __restrict__ el, float* __restrict__ er) {
  int gw = (blockIdx.x * 256 + threadIdx.x) >> 6;
  int lane = threadIdx.x & 63;
  if (gw >= 4 * N_DST) return;
  if (gw < N_DST) {
    int n = gw;
    float v = h_dst[(size_t)n * HDIM + lane];
#pragma unroll
    for (int r = 0; r < RREL; r++) {
      float p = v * attn_r[r * HDIM + lane];
#pragma unroll
      for (int o = 32; o > 0; o >>= 1) p += __shfl_xor(p, o);
      if (lane == 0) er[r * N_DST + n] = p;
    }
  } else {
    int t = gw - N_DST;
    int r = t / N_DST;
    int n = t - r * N_DST;
    float v = h_src[((size_t)r * N_DST + n) * HDIM + lane];
    float p = v * attn_l[r * HDIM + lane];
#pragma unroll
    for (int o = 32; o > 0; o >>= 1) p += __shfl_xor(p, o);
    if (lane == 0) el[r * N_DST + n] = p;
  }
}

// ---------------- CSR build: histogram -> scan -> scatter ----------------
__global__ __launch_bounds__(256) void k_count(const int* __restrict__ dst, int* counts) {
  int idx = blockIdx.x * 256 + threadIdx.x;
  if (idx >= RREL * NE) return;
  int r = idx / NE;
  atomicAdd(&counts[r * N_DST + dst[idx]], 1);
}

__global__ __launch_bounds__(256) void k_scan1(const int* __restrict__ counts,
                                               int* __restrict__ offsets,
                                               int* __restrict__ partials, int ntot) {
  __shared__ int sm[256];
  int tid = threadIdx.x;
  int base = blockIdx.x * 1024 + tid * 4;
  int c[4];
#pragma unroll
  for (int k = 0; k < 4; k++) c[k] = (base + k < ntot) ? counts[base + k] : 0;
  int tsum = c[0] + c[1] + c[2] + c[3];
  sm[tid] = tsum;
  __syncthreads();
  for (int off = 1; off < 256; off <<= 1) {
    int v = (tid >= off) ? sm[tid - off] : 0;
    __syncthreads();
    sm[tid] += v;
    __syncthreads();
  }
  if (tid == 255) partials[blockIdx.x] = sm[255];
  int run = sm[tid] - tsum;  // exclusive base for this thread
#pragma unroll
  for (int k = 0; k < 4; k++) {
    if (base + k < ntot) offsets[base + k] = run;
    run += c[k];
  }
}

__global__ __launch_bounds__(512) void k_scan2(int* partials, int nb) {
  __shared__ int sm[512];
  int tid = threadIdx.x;
  int v = (tid < nb) ? partials[tid] : 0;
  sm[tid] = v;
  __syncthreads();
  for (int off = 1; off < 512; off <<= 1) {
    int t = (tid >= off) ? sm[tid - off] : 0;
    __syncthreads();
    sm[tid] += t;
    __syncthreads();
  }
  if (tid < nb) partials[tid] = sm[tid] - v;  // exclusive
}

__global__ __launch_bounds__(256) void k_scan3(int* __restrict__ offsets,
                                               int* __restrict__ cursor,
                                               const int* __restrict__ partials,
                                               int ntot, int total) {
  int add = partials[blockIdx.x];
  int base = blockIdx.x * 1024 + threadIdx.x * 4;
#pragma unroll
  for (int k = 0; k < 4; k++) {
    int i = base + k;
    if (i < ntot) {
      int v = offsets[i] + add;
      offsets[i] = v;
      cursor[i] = v;
    }
  }
  if (blockIdx.x == 0 && threadIdx.x == 0) offsets[ntot] = total;
}

__global__ __launch_bounds__(256) void k_scatter(const int* __restrict__ src,
                                                 const int* __restrict__ dst,
                                                 int* __restrict__ cursor,
                                                 int* __restrict__ src_sorted) {
  int idx = blockIdx.x * 256 + threadIdx.x;
  if (idx >= RREL * NE) return;
  int r = idx / NE;
  int pos = atomicAdd(&cursor[r * N_DST + dst[idx]], 1);
  src_sorted[pos] = src[idx];
}

// ---------------- GAT aggregation: one wave per (relation, dst-node) ----------------
// exp without max-subtraction is safe: leaky_relu output in [~-0.05, ~4.5].
__global__ __launch_bounds__(256) void k_aggregate(
    const int* __restrict__ offsets, const int* __restrict__ src_sorted,
    const float* __restrict__ el, const float* __restrict__ er,
    const float* __restrict__ h_src, float* __restrict__ zbuf) {
  int gw = (blockIdx.x * 256 + threadIdx.x) >> 6;
  int lane = threadIdx.x & 63;
  if (gw >= RREL * N_DST) return;
  int r = gw / N_DST;
  int start = offsets[gw], end = offsets[gw + 1];
  float erv = er[gw];
  const float* hs = h_src + (size_t)r * N_DST * HDIM;
  const float* elr = el + (size_t)r * N_DST;
  float acc = 0.f, ssum = 0.f;
  for (int base = start; base < end; base += 64) {
    int cnt = end - base;
    if (cnt > 64) cnt = 64;
    float a = 0.f;
    int sidx = 0;
    if (lane < cnt) {
      sidx = src_sorted[base + lane];
      float x = elr[sidx] + erv;
      x = (x > 0.f) ? x : 0.01f * x;  // leaky_relu
      a = __expf(x);
    }
    ssum += a;
    for (int e = 0; e < cnt; e++) {
      float ae = __shfl(a, e);
      int se = __shfl(sidx, e);
      acc += ae * hs[(size_t)se * HDIM + lane];
    }
  }
#pragma unroll
  for (int o = 32; o > 0; o >>= 1) ssum += __shfl_xor(ssum, o);
  float zv = 0.f;
  if (end > start) {
    float v = acc / ssum;
    zv = (v > 0.f) ? v : (__expf(v) - 1.f);  // elu
  }
  zbuf[(size_t)gw * HDIM + lane] = zv;
}

// ---------------- semantic attention reduce: w[r] = sum_n tanh(z@W1+b1)@w2 ----------------
// 64 rows x 128 cols per block; 8x4 register tile; block-local partials -> 3 atomics.
__global__ __launch_bounds__(256) void k_semantic(
    const float* __restrict__ zbuf, const float* __restrict__ W1,
    const float* __restrict__ b1, const float* __restrict__ w2,
    float* __restrict__ w_acc) {
  __shared__ float W1l[64 * 128];  // 32 KB
  __shared__ float zsh[64 * 68];   // 17.4 KB, +4 pad
  __shared__ float wsum[RREL];
  int tid = threadIdx.x;
  if (tid < RREL) wsum[tid] = 0.f;
  for (int i = tid * 4; i < 64 * 128; i += 1024)
    *(float4*)(W1l + i) = *(const float4*)(W1 + i);
  long row0 = (long)blockIdx.x * 64;
  for (int t4 = tid; t4 < 1024; t4 += 256) {
    int rl = t4 >> 4;
    int j4 = (t4 & 15) << 2;
    long row = row0 + rl;
    float4 v = make_float4(0.f, 0.f, 0.f, 0.f);
    if (row < (long)RREL * N_DST) v = *(const float4*)(zbuf + row * HDIM + j4);
    *(float4*)(zsh + rl * 68 + j4) = v;
  }
  __syncthreads();
  int tc = tid & 31;  // cols 4*tc (0..124)
  int tr = tid >> 5;  // rows 8*tr+i
  float acc[8][4] = {};
#pragma unroll
  for (int jj = 0; jj < 64; jj += 4) {
    float4 zv[8], wv[4];
#pragma unroll
    for (int i = 0; i < 8; i++) zv[i] = *(float4*)(zsh + (8 * tr + i) * 68 + jj);
#pragma unroll
    for (int j = 0; j < 4; j++) wv[j] = *(float4*)(W1l + (jj + j) * 128 + 4 * tc);
#pragma unroll
    for (int i = 0; i < 8; i++) {
      const float* zp = (const float*)&zv[i];
#pragma unroll
      for (int j = 0; j < 4; j++) {
        const float* wp = (const float*)&wv[j];
        float zz = zp[j];
#pragma unroll
        for (int c = 0; c < 4; c++) acc[i][c] += zz * wp[c];
      }
    }
  }
  float b1v[4], w2v[4];
#pragma unroll
  for (int c = 0; c < 4; c++) {
    b1v[c] = b1[4 * tc + c];
    w2v[c] = w2[4 * tc + c];
  }
#pragma unroll
  for (int i = 0; i < 8; i++) {
    long row = row0 + 8 * tr + i;
    float p = 0.f;
#pragma unroll
    for (int c = 0; c < 4; c++) {
      float x = acc[i][c] + b1v[c];
      float ex = __expf(2.f * x);
      p += (1.f - 2.f / (ex + 1.f)) * w2v[c];  // tanh
    }
#pragma unroll
    for (int o = 16; o > 0; o >>= 1) p += __shfl_xor(p, o);  // reduce 32 col-lanes
    if (tc == 0 && row < (long)RREL * N_DST) {
      int r = (int)(row / N_DST);
      atomicAdd(&wsum[r], p);
    }
  }
  __syncthreads();
  if (tid < RREL) atomicAdd(&w_acc[tid], wsum[tid]);
}

// ---------------- softmax over relations + weighted combine ----------------
__global__ __launch_bounds__(256) void k_final(const float* __restrict__ zbuf,
                                               const float* __restrict__ w_acc,
                                               float* __restrict__ out) {
  int idx = blockIdx.x * 256 + threadIdx.x;  // float4 index over N*H/4
  if (idx >= N_DST * HDIM / 4) return;
  const float invN = 1.0f / N_DST;
  float w0 = w_acc[0] * invN, w1 = w_acc[1] * invN, w2v = w_acc[2] * invN;
  float m = fmaxf(w0, fmaxf(w1, w2v));
  float e0 = __expf(w0 - m), e1 = __expf(w1 - m), e2 = __expf(w2v - m);
  float inv = 1.f / (e0 + e1 + e2);
  e0 *= inv; e1 *= inv; e2 *= inv;
  size_t o = (size_t)idx * 4;
  const size_t stride = (size_t)N_DST * HDIM;
  float4 z0 = *(const float4*)(zbuf + o);
  float4 z1 = *(const float4*)(zbuf + stride + o);
  float4 z2 = *(const float4*)(zbuf + 2 * stride + o);
  float4 r;
  r.x = e0 * z0.x + e1 * z1.x + e2 * z2.x;
  r.y = e0 * z0.y + e1 * z1.y + e2 * z2.y;
  r.z = e0 * z0.z + e1 * z1.z + e2 * z2.z;
  r.w = e0 * z0.w + e1 * z1.w + e2 * z2.w;
  *(float4*)(out + o) = r;
}

extern "C" void kernel_launch(void* const* d_in, const int* in_sizes, int n_in,
                              void* d_out, int out_size, void* d_ws, size_t ws_size,
                              hipStream_t stream) {
  const float* dst_feat = (const float*)d_in[0];
  const float* neigh = (const float*)d_in[1];
  const float* Wt = (const float*)d_in[2];
  const float* bt = (const float*)d_in[3];
  const float* attn_l = (const float*)d_in[4];
  const float* attn_r = (const float*)d_in[5];
  const float* W1 = (const float*)d_in[6];
  const float* b1 = (const float*)d_in[7];
  const float* w2 = (const float*)d_in[8];
  const int* src_idx = (const int*)d_in[9];
  const int* dst_idx = (const int*)d_in[10];
  float* out = (float*)d_out;

  char* p = (char*)d_ws;
  auto alloc = [&](size_t bytes) {
    char* q = p;
    p += (bytes + 255) & ~(size_t)255;
    return (void*)q;
  };
  float* h_dst = (float*)alloc((size_t)N_DST * HDIM * 4);
  float* h_src = (float*)alloc((size_t)RREL * N_DST * HDIM * 4);
  float* el = (float*)alloc((size_t)RREL * N_DST * 4);
  float* er = (float*)alloc((size_t)RREL * N_DST * 4);
  float* zbuf = (float*)alloc((size_t)RREL * N_DST * HDIM * 4);
  float* w_acc = (float*)alloc(64);
  int* counts = (int*)alloc((size_t)RREL * N_DST * 4);
  int* offsets = (int*)alloc(((size_t)RREL * N_DST + 1) * 4);
  int* cursor = (int*)alloc((size_t)RREL * N_DST * 4);
  int* partials = (int*)alloc(512 * 4);
  int* src_sorted = (int*)alloc((size_t)RREL * NE * 4);
  // total ~197 MB of d_ws

  hipMemsetAsync(counts, 0, (size_t)RREL * N_DST * 4, stream);
  hipMemsetAsync(w_acc, 0, 64, stream);

  const int NSEG = RREL * N_DST;             // 300000
  const int NB1 = (NSEG + 1023) / 1024;      // 293

  k_gemm<<<4 * ((N_DST + 63) / 64), 256, 0, stream>>>(dst_feat, neigh, Wt, bt, h_dst, h_src);
  k_logits<<<(4 * N_DST * 64) / 256, 256, 0, stream>>>(h_dst, h_src, attn_l, attn_r, el, er);
  k_count<<<(RREL * NE + 255) / 256, 256, 0, stream>>>(dst_idx, counts);
  k_scan1<<<NB1, 256, 0, stream>>>(counts, offsets, partials, NSEG);
  k_scan2<<<1, 512, 0, stream>>>(partials, NB1);
  k_scan3<<<NB1, 256, 0, stream>>>(offsets, cursor, partials, NSEG, RREL * NE);
  k_scatter<<<(RREL * NE + 255) / 256, 256, 0, stream>>>(src_idx, dst_idx, cursor, src_sorted);
  k_aggregate<<<(RREL * N_DST * 64) / 256, 256, 0, stream>>>(offsets, src_sorted, el, er, h_src, zbuf);
  k_semantic<<<(NSEG + 63) / 64, 256, 0, stream>>>(zbuf, W1, b1, w2, w_acc);
  k_final<<<(N_DST * HDIM / 4 + 255) / 256, 256, 0, stream>>>(zbuf, w_acc, out);
}

// Round 3
// 1082.662 us; speedup vs baseline: 1.5302x; 1.5302x over previous
//
#include <hip/hip_runtime.h>

#define N_DST 100000
#define DIN 128
#define HDIM 64
#define RREL 3
#define NE 1000000

// ---------------- GEMM: h = A @ W + b  (4 matrices: dst + 3 relations) ----------------
// 64-row x 64-col tile per block, 256 threads, 4x4 register tile per thread.
__global__ __launch_bounds__(256) void k_gemm(
    const float* __restrict__ dst_feat, const float* __restrict__ neigh,
    const float* __restrict__ Wt, const float* __restrict__ bt,
    float* __restrict__ h_dst, float* __restrict__ h_src) {
  const int RB = (N_DST + 63) / 64;  // 1563 row-blocks per matrix
  int mat = blockIdx.x / RB;
  int row0 = (blockIdx.x % RB) * 64;
  const float* A = (mat == 0) ? dst_feat : (neigh + (size_t)(mat - 1) * N_DST * DIN);
  float* Hout = (mat == 0) ? h_dst : (h_src + (size_t)(mat - 1) * N_DST * HDIM);
  const float* W = Wt + (size_t)mat * DIN * HDIM;
  const float* b = bt + mat * HDIM;

  __shared__ float Wl[DIN * HDIM];  // 32 KB
  __shared__ float Al[64 * 36];     // 64 rows x 32-k chunk, stride 36 (bank-safe), 9.2 KB

  int tid = threadIdx.x;
  for (int i = tid * 4; i < DIN * HDIM; i += 1024)
    *(float4*)(Wl + i) = *(const float4*)(W + i);

  int tc = tid & 15;  // cols 4*tc .. 4*tc+3
  int tr = tid >> 4;  // rows 4*tr .. 4*tr+3
  float acc[4][4] = {};

  for (int k0 = 0; k0 < DIN; k0 += 32) {
    __syncthreads();
    for (int s = tid; s < 512; s += 256) {
      int r = s >> 3;
      int kq = (s & 7) << 2;
      int gr = row0 + r;
      if (gr >= N_DST) gr = N_DST - 1;  // clamp (tail block)
      *(float4*)(Al + r * 36 + kq) = *(const float4*)(A + (size_t)gr * DIN + k0 + kq);
    }
    __syncthreads();
#pragma unroll
    for (int kk = 0; kk < 32; kk += 4) {
      float4 av[4], wv[4];
#pragma unroll
      for (int i = 0; i < 4; i++) av[i] = *(float4*)(Al + (4 * tr + i) * 36 + kk);
#pragma unroll
      for (int j = 0; j < 4; j++) wv[j] = *(float4*)(Wl + (k0 + kk + j) * HDIM + 4 * tc);
#pragma unroll
      for (int i = 0; i < 4; i++) {
        const float* ap = (const float*)&av[i];
#pragma unroll
        for (int j = 0; j < 4; j++) {
          const float* wp = (const float*)&wv[j];
          float a = ap[j];
#pragma unroll
          for (int c = 0; c < 4; c++) acc[i][c] += a * wp[c];
        }
      }
    }
  }
#pragma unroll
  for (int i = 0; i < 4; i++) {
    int gr = row0 + 4 * tr + i;
    if (gr < N_DST) {
      float4 o;
      float* op = (float*)&o;
#pragma unroll
      for (int c = 0; c < 4; c++) op[c] = acc[i][c] + b[4 * tc + c];
      *(float4*)(Hout + (size_t)gr * HDIM + 4 * tc) = o;
    }
  }
}

// ---------------- per-node attention logits: er[r][n]=h_dst[n].ar[r], el[r][n]=h_src[r][n].al[r]
__global__ __launch_bounds__(256) void k_logits(
    const float* __restrict__ h_dst, const float* __restrict__ h_src,
    const float* __restrict__ attn_l, const float* __restrict__ attn_r,
    float* __restrict__ el, float* __restrict__ er) {
  int gw = (blockIdx.x * 256 + threadIdx.x) >> 6;
  int lane = threadIdx.x & 63;
  if (gw >= 4 * N_DST) return;
  if (gw < N_DST) {
    int n = gw;
    float v = h_dst[(size_t)n * HDIM + lane];
#pragma unroll
    for (int r = 0; r < RREL; r++) {
      float p = v * attn_r[r * HDIM + lane];
#pragma unroll
      for (int o = 32; o > 0; o >>= 1) p += __shfl_xor(p, o);
      if (lane == 0) er[r * N_DST + n] = p;
    }
  } else {
    int t = gw - N_DST;
    int r = t / N_DST;
    int n = t - r * N_DST;
    float v = h_src[((size_t)r * N_DST + n) * HDIM + lane];
    float p = v * attn_l[r * HDIM + lane];
#pragma unroll
    for (int o = 32; o > 0; o >>= 1) p += __shfl_xor(p, o);
    if (lane == 0) el[r * N_DST + n] = p;
  }
}

// ---------------- CSR build: histogram -> scan -> scatter ----------------
__global__ __launch_bounds__(256) void k_count(const int* __restrict__ dst, int* counts) {
  int idx = blockIdx.x * 256 + threadIdx.x;
  if (idx >= RREL * NE) return;
  int r = idx / NE;
  atomicAdd(&counts[r * N_DST + dst[idx]], 1);
}

__global__ __launch_bounds__(256) void k_scan1(const int* __restrict__ counts,
                                               int* __restrict__ offsets,
                                               int* __restrict__ partials, int ntot) {
  __shared__ int sm[256];
  int tid = threadIdx.x;
  int base = blockIdx.x * 1024 + tid * 4;
  int c[4];
#pragma unroll
  for (int k = 0; k < 4; k++) c[k] = (base + k < ntot) ? counts[base + k] : 0;
  int tsum = c[0] + c[1] + c[2] + c[3];
  sm[tid] = tsum;
  __syncthreads();
  for (int off = 1; off < 256; off <<= 1) {
    int v = (tid >= off) ? sm[tid - off] : 0;
    __syncthreads();
    sm[tid] += v;
    __syncthreads();
  }
  if (tid == 255) partials[blockIdx.x] = sm[255];
  int run = sm[tid] - tsum;  // exclusive base for this thread
#pragma unroll
  for (int k = 0; k < 4; k++) {
    if (base + k < ntot) offsets[base + k] = run;
    run += c[k];
  }
}

__global__ __launch_bounds__(512) void k_scan2(int* partials, int nb) {
  __shared__ int sm[512];
  int tid = threadIdx.x;
  int v = (tid < nb) ? partials[tid] : 0;
  sm[tid] = v;
  __syncthreads();
  for (int off = 1; off < 512; off <<= 1) {
    int t = (tid >= off) ? sm[tid - off] : 0;
    __syncthreads();
    sm[tid] += t;
    __syncthreads();
  }
  if (tid < nb) partials[tid] = sm[tid] - v;  // exclusive
}

__global__ __launch_bounds__(256) void k_scan3(int* __restrict__ offsets,
                                               int* __restrict__ cursor,
                                               const int* __restrict__ partials,
                                               int ntot, int total) {
  int add = partials[blockIdx.x];
  int base = blockIdx.x * 1024 + threadIdx.x * 4;
#pragma unroll
  for (int k = 0; k < 4; k++) {
    int i = base + k;
    if (i < ntot) {
      int v = offsets[i] + add;
      offsets[i] = v;
      cursor[i] = v;
    }
  }
  if (blockIdx.x == 0 && threadIdx.x == 0) offsets[ntot] = total;
}

__global__ __launch_bounds__(256) void k_scatter(const int* __restrict__ src,
                                                 const int* __restrict__ dst,
                                                 int* __restrict__ cursor,
                                                 int* __restrict__ src_sorted) {
  int idx = blockIdx.x * 256 + threadIdx.x;
  if (idx >= RREL * NE) return;
  int r = idx / NE;
  int pos = atomicAdd(&cursor[r * N_DST + dst[idx]], 1);
  src_sorted[pos] = src[idx];
}

// ---------------- GAT aggregation: one wave per (relation, dst-node) ----------------
// exp without max-subtraction is safe: leaky_relu output in [~-0.05, ~4.5].
__global__ __launch_bounds__(256) void k_aggregate(
    const int* __restrict__ offsets, const int* __restrict__ src_sorted,
    const float* __restrict__ el, const float* __restrict__ er,
    const float* __restrict__ h_src, float* __restrict__ zbuf) {
  int gw = (blockIdx.x * 256 + threadIdx.x) >> 6;
  int lane = threadIdx.x & 63;
  if (gw >= RREL * N_DST) return;
  int r = gw / N_DST;
  int start = offsets[gw], end = offsets[gw + 1];
  float erv = er[gw];
  const float* hs = h_src + (size_t)r * N_DST * HDIM;
  const float* elr = el + (size_t)r * N_DST;
  float acc = 0.f, ssum = 0.f;
  for (int base = start; base < end; base += 64) {
    int cnt = end - base;
    if (cnt > 64) cnt = 64;
    float a = 0.f;
    int sidx = 0;
    if (lane < cnt) {
      sidx = src_sorted[base + lane];
      float x = elr[sidx] + erv;
      x = (x > 0.f) ? x : 0.01f * x;  // leaky_relu
      a = __expf(x);
    }
    ssum += a;
    for (int e = 0; e < cnt; e++) {
      float ae = __shfl(a, e);
      int se = __shfl(sidx, e);
      acc += ae * hs[(size_t)se * HDIM + lane];
    }
  }
#pragma unroll
  for (int o = 32; o > 0; o >>= 1) ssum += __shfl_xor(ssum, o);
  float zv = 0.f;
  if (end > start) {
    float v = acc / ssum;
    zv = (v > 0.f) ? v : (__expf(v) - 1.f);  // elu
  }
  zbuf[(size_t)gw * HDIM + lane] = zv;
}

// ---------------- semantic attention reduce: w[r] = sum_n tanh(z@W1+b1)@w2 ----------------
// 64 rows x 128 cols per block; 8x4 register tile computed in two 4-row half-steps
// (jj loop NOT unrolled: full unroll ×16 previously blew past 256 VGPRs and spilled
// ~1.5 GB of scratch traffic per dispatch — 681 us. Peak live regs now ~75.)
__global__ __launch_bounds__(256) void k_semantic(
    const float* __restrict__ zbuf, const float* __restrict__ W1,
    const float* __restrict__ b1, const float* __restrict__ w2,
    float* __restrict__ w_acc) {
  __shared__ float W1l[64 * 128];  // 32 KB
  __shared__ float zsh[64 * 68];   // 17.4 KB, +4 pad
  __shared__ float wsum[RREL];
  int tid = threadIdx.x;
  if (tid < RREL) wsum[tid] = 0.f;
  for (int i = tid * 4; i < 64 * 128; i += 1024)
    *(float4*)(W1l + i) = *(const float4*)(W1 + i);
  long row0 = (long)blockIdx.x * 64;
  for (int t4 = tid; t4 < 1024; t4 += 256) {
    int rl = t4 >> 4;
    int j4 = (t4 & 15) << 2;
    long row = row0 + rl;
    float4 v = make_float4(0.f, 0.f, 0.f, 0.f);
    if (row < (long)RREL * N_DST) v = *(const float4*)(zbuf + row * HDIM + j4);
    *(float4*)(zsh + rl * 68 + j4) = v;
  }
  __syncthreads();
  int tc = tid & 31;  // cols 4*tc (0..124)
  int tr = tid >> 5;  // rows 8*tr+i
  float acc[8][4] = {};
#pragma unroll 1
  for (int jj = 0; jj < 64; jj += 4) {
    float4 wv[4];
#pragma unroll
    for (int j = 0; j < 4; j++) wv[j] = *(float4*)(W1l + (jj + j) * 128 + 4 * tc);
#pragma unroll
    for (int ih = 0; ih < 2; ih++) {
      float4 zv[4];
#pragma unroll
      for (int i = 0; i < 4; i++) zv[i] = *(float4*)(zsh + (8 * tr + 4 * ih + i) * 68 + jj);
#pragma unroll
      for (int i = 0; i < 4; i++) {
        const float* zp = (const float*)&zv[i];
#pragma unroll
        for (int j = 0; j < 4; j++) {
          const float* wp = (const float*)&wv[j];
          float zz = zp[j];
#pragma unroll
          for (int c = 0; c < 4; c++) acc[4 * ih + i][c] += zz * wp[c];
        }
      }
    }
  }
  float b1v[4], w2v[4];
#pragma unroll
  for (int c = 0; c < 4; c++) {
    b1v[c] = b1[4 * tc + c];
    w2v[c] = w2[4 * tc + c];
  }
#pragma unroll
  for (int i = 0; i < 8; i++) {
    long row = row0 + 8 * tr + i;
    float p = 0.f;
#pragma unroll
    for (int c = 0; c < 4; c++) {
      float x = acc[i][c] + b1v[c];
      float ex = __expf(2.f * x);
      p += (1.f - 2.f / (ex + 1.f)) * w2v[c];  // tanh
    }
#pragma unroll
    for (int o = 16; o > 0; o >>= 1) p += __shfl_xor(p, o);  // reduce 32 col-lanes
    if (tc == 0 && row < (long)RREL * N_DST) {
      int r = (int)(row / N_DST);
      atomicAdd(&wsum[r], p);
    }
  }
  __syncthreads();
  if (tid < RREL) atomicAdd(&w_acc[tid], wsum[tid]);
}

// ---------------- softmax over relations + weighted combine ----------------
__global__ __launch_bounds__(256) void k_final(const float* __restrict__ zbuf,
                                               const float* __restrict__ w_acc,
                                               float* __restrict__ out) {
  int idx = blockIdx.x * 256 + threadIdx.x;  // float4 index over N*H/4
  if (idx >= N_DST * HDIM / 4) return;
  const float invN = 1.0f / N_DST;
  float w0 = w_acc[0] * invN, w1 = w_acc[1] * invN, w2v = w_acc[2] * invN;
  float m = fmaxf(w0, fmaxf(w1, w2v));
  float e0 = __expf(w0 - m), e1 = __expf(w1 - m), e2 = __expf(w2v - m);
  float inv = 1.f / (e0 + e1 + e2);
  e0 *= inv; e1 *= inv; e2 *= inv;
  size_t o = (size_t)idx * 4;
  const size_t stride = (size_t)N_DST * HDIM;
  float4 z0 = *(const float4*)(zbuf + o);
  float4 z1 = *(const float4*)(zbuf + stride + o);
  float4 z2 = *(const float4*)(zbuf + 2 * stride + o);
  float4 r;
  r.x = e0 * z0.x + e1 * z1.x + e2 * z2.x;
  r.y = e0 * z0.y + e1 * z1.y + e2 * z2.y;
  r.z = e0 * z0.z + e1 * z1.z + e2 * z2.z;
  r.w = e0 * z0.w + e1 * z1.w + e2 * z2.w;
  *(float4*)(out + o) = r;
}

extern "C" void kernel_launch(void* const* d_in, const int* in_sizes, int n_in,
                              void* d_out, int out_size, void* d_ws, size_t ws_size,
                              hipStream_t stream) {
  const float* dst_feat = (const float*)d_in[0];
  const float* neigh = (const float*)d_in[1];
  const float* Wt = (const float*)d_in[2];
  const float* bt = (const float*)d_in[3];
  const float* attn_l = (const float*)d_in[4];
  const float* attn_r = (const float*)d_in[5];
  const float* W1 = (const float*)d_in[6];
  const float* b1 = (const float*)d_in[7];
  const float* w2 = (const float*)d_in[8];
  const int* src_idx = (const int*)d_in[9];
  const int* dst_idx = (const int*)d_in[10];
  float* out = (float*)d_out;

  char* p = (char*)d_ws;
  auto alloc = [&](size_t bytes) {
    char* q = p;
    p += (bytes + 255) & ~(size_t)255;
    return (void*)q;
  };
  float* h_dst = (float*)alloc((size_t)N_DST * HDIM * 4);
  float* h_src = (float*)alloc((size_t)RREL * N_DST * HDIM * 4);
  float* el = (float*)alloc((size_t)RREL * N_DST * 4);
  float* er = (float*)alloc((size_t)RREL * N_DST * 4);
  float* zbuf = (float*)alloc((size_t)RREL * N_DST * HDIM * 4);
  float* w_acc = (float*)alloc(64);
  int* counts = (int*)alloc((size_t)RREL * N_DST * 4);
  int* offsets = (int*)alloc(((size_t)RREL * N_DST + 1) * 4);
  int* cursor = (int*)alloc((size_t)RREL * N_DST * 4);
  int* partials = (int*)alloc(512 * 4);
  int* src_sorted = (int*)alloc((size_t)RREL * NE * 4);
  // total ~197 MB of d_ws

  hipMemsetAsync(counts, 0, (size_t)RREL * N_DST * 4, stream);
  hipMemsetAsync(w_acc, 0, 64, stream);

  const int NSEG = RREL * N_DST;             // 300000
  const int NB1 = (NSEG + 1023) / 1024;      // 293

  k_gemm<<<4 * ((N_DST + 63) / 64), 256, 0, stream>>>(dst_feat, neigh, Wt, bt, h_dst, h_src);
  k_logits<<<(4 * N_DST * 64) / 256, 256, 0, stream>>>(h_dst, h_src, attn_l, attn_r, el, er);
  k_count<<<(RREL * NE + 255) / 256, 256, 0, stream>>>(dst_idx, counts);
  k_scan1<<<NB1, 256, 0, stream>>>(counts, offsets, partials, NSEG);
  k_scan2<<<1, 512, 0, stream>>>(partials, NB1);
  k_scan3<<<NB1, 256, 0, stream>>>(offsets, cursor, partials, NSEG, RREL * NE);
  k_scatter<<<(RREL * NE + 255) / 256, 256, 0, stream>>>(src_idx, dst_idx, cursor, src_sorted);
  k_aggregate<<<(RREL * N_DST * 64) / 256, 256, 0, stream>>>(offsets, src_sorted, el, er, h_src, zbuf);
  k_semantic<<<(NSEG + 63) / 64, 256, 0, stream>>>(zbuf, W1, b1, w2, w_acc);
  k_final<<<(N_DST * HDIM / 4 + 255) / 256, 256, 0, stream>>>(zbuf, w_acc, out);
}